// Round 14
// baseline (40.725 us; speedup 1.0000x reference)
//
#include <hip/hip_runtime.h>
#include <hip/hip_bf16.h>

#define D_IN  128
#define D_HID 256
#define NBLK  256
#define NTHR  512
#define NT_C  512
#define MAXG  512
#define HASHN 2048
#define PBM_STRIDE 72
#define PBC_STRIDE 516

// ws int layout:
//  [0..7]        barrier slots for kernel C (zeroed by AB block 0)
//  [16]          m (compact match count, written by AB block 0)
//  [1024..19456] per-block match regions (NBLK x PBM_STRIDE: header=count+1, then <=64 srcs)
//  [20480..]     compact match src list (MAXG)
//  [21504..]     map j -> representative index r (MAXG+1 entries, j=0 agent)
//  [40960..]     per-block degree partials (NBLK x PBC_STRIDE, overwrite-only)
//  floats:       [303104]=h0[256], [303616]=h1raw[256], [304128]=h2raw[256]
#define OFF_BAR  0
#define OFF_M    16
#define OFF_PBM  1024
#define OFF_CM   20480
#define OFF_MAP  21504
#define OFF_PBC  40960
#define OFF_H0   303104
#define OFF_H1   303616
#define OFF_H2   304128

#define ALD(p)   __hip_atomic_load((p),      __ATOMIC_RELAXED, __HIP_MEMORY_SCOPE_AGENT)
#define AST(p,v) __hip_atomic_store((p),(v), __ATOMIC_RELAXED, __HIP_MEMORY_SCOPE_AGENT)

__device__ __forceinline__ float ldf(const void* p, long long i, bool b16) {
    if (b16) {
        unsigned short u = ((const unsigned short*)p)[i];
        return __uint_as_float(((unsigned int)u) << 16);
    }
    return ((const float*)p)[i];
}

// paired load of elements i, i+1 (i even)
__device__ __forceinline__ void ld2(const void* p, long long i, bool b16, float& a, float& b) {
    if (b16) {
        unsigned int u = ((const unsigned int*)p)[i >> 1];
        a = __uint_as_float(u << 16);
        b = __uint_as_float(u & 0xffff0000u);
    } else {
        float2 v = ((const float2*)p)[i >> 1];
        a = v.x; b = v.y;
    }
}

__device__ __forceinline__ unsigned hash_n(int key) {
    return (((unsigned)key * 2654435761u) >> 21) & (HASHN - 1);
}

__device__ __forceinline__ int detect_i64(const void* edges, int tid, int* s) {
    if (tid < 64) {
        const unsigned* w = (const unsigned*)edges;
        unsigned long long b = __ballot(w[2 * tid + 1] == 0u);
        if (tid == 0) *s = (b == ~0ULL) ? 1 : 0;
    }
    __syncthreads();
    return *s;
}

__device__ __forceinline__ int detect_b16(const void* state, int tid, int* s) {
    if (tid < 64) {
        const unsigned short* p = (const unsigned short*)state;
        unsigned short v = p[tid];
        int e = (v >> 7) & 0xff;
        unsigned long long b = __ballot(v == 0 || (e >= 90 && e <= 140));
        if (tid == 0) *s = (b == ~0ULL) ? 1 : 0;
    }
    __syncthreads();
    return *s;
}

// producer-side arrival: one fenced RELEASE add, no spin.
__device__ __forceinline__ void bar_arrive(int* slot) {
    __syncthreads();
    if (threadIdx.x == 0) {
        __threadfence();
        __hip_atomic_fetch_add(slot, 1, __ATOMIC_RELEASE, __HIP_MEMORY_SCOPE_AGENT);
    }
}

// consumer-side wait: RELAXED spin (R8 lesson), fence on exit.
__device__ __forceinline__ void bar_wait(int* slot, int cnt) {
    if (threadIdx.x == 0) {
        while (__hip_atomic_load(slot, __ATOMIC_RELAXED, __HIP_MEMORY_SCOPE_AGENT) < cnt)
            __builtin_amdgcn_s_sleep(2);
        __threadfence();
    }
    __syncthreads();
}

// AB: fused match-scan + degree-count. Phase 1 scans own slice for matches,
// publishes region {srcs, fence, header=count+1}. Phase 2 polls all headers
// valid (value-stable across replays -> instant on replay), rebuilds the
// compact list, hashes it, re-scans the SAME slice (L2-hot) for degrees, and
// overwrites its private partial-count region. Block 0 exports M/CM/MAP.
__global__ void __launch_bounds__(NTHR) k_AB(const void* edges, const void* state,
                                             const int* agent_p,
                                             const void* w0, const void* w1,
                                             const void* w2, const void* w3,
                                             int* wsi, long long n_edges) {
    __shared__ int s_pref[NTHR];
    __shared__ int s_list[64];
    __shared__ int s_nodes[MAXG + 1];
    __shared__ int s_hkey[HASHN];
    __shared__ int s_hval[HASHN];
    __shared__ int s_cnt[MAXG + 1];
    __shared__ int s_i64, s_b16;
    int tid = threadIdx.x, bid = blockIdx.x;
    int i64 = detect_i64(edges, tid, &s_i64);
    bool b16 = detect_b16(state, tid, &s_b16) != 0;

    if (bid == 0 && tid < 8) AST(&wsi[OFF_BAR + tid], 0);

    // weight L3-prefetch: one dword per 64B line, spread over the grid
    {
        int esz = b16 ? 2 : 4;
        long long gt = (long long)bid * NTHR + tid;
        const void* arr[4] = { w0, w1, w2, w3 };
        const int elems[4] = { D_IN * D_HID, D_HID * D_HID, D_HID * D_HID, D_HID * 8 };
        long long base = 0;
        #pragma unroll
        for (int a = 0; a < 4; a++) {
            long long lines = ((long long)elems[a] * esz) >> 6;
            long long idx = gt - base;
            if (idx >= 0 && idx < lines) {
                unsigned v = *(const unsigned*)((const char*)arr[a] + (idx << 6));
                asm volatile("" :: "v"(v));
            }
            base += lines;
        }
    }

    // ---- phase 1: 8-wide match scan over own slice ----
    int agent = agent_p[0];
    long long base8 = ((long long)bid * NTHR + tid) * 8;
    const long long stride8 = (long long)NBLK * NTHR * 8;
    long long nv = n_edges & ~7LL;
    int c = 0;
    if (i64) {
        const long long* dst = (const long long*)edges + n_edges;
        for (long long e = base8; e < nv; e += stride8) {
            long2 a0 = *(const long2*)(dst + e);
            long2 a1 = *(const long2*)(dst + e + 2);
            long2 a2 = *(const long2*)(dst + e + 4);
            long2 a3 = *(const long2*)(dst + e + 6);
            c += ((int)a0.x == agent) + ((int)a0.y == agent)
               + ((int)a1.x == agent) + ((int)a1.y == agent)
               + ((int)a2.x == agent) + ((int)a2.y == agent)
               + ((int)a3.x == agent) + ((int)a3.y == agent);
        }
        if (bid == 0 && tid == 0)
            for (long long e = nv; e < n_edges; e++) c += ((int)dst[e] == agent);
    } else {
        const int* dst = (const int*)edges + n_edges;
        for (long long e = base8; e < nv; e += stride8) {
            int4 a = *(const int4*)(dst + e);
            int4 b = *(const int4*)(dst + e + 4);
            c += (a.x == agent) + (a.y == agent) + (a.z == agent) + (a.w == agent)
               + (b.x == agent) + (b.y == agent) + (b.z == agent) + (b.w == agent);
        }
        if (bid == 0 && tid == 0)
            for (long long e = nv; e < n_edges; e++) c += (dst[e] == agent);
    }
    s_pref[tid] = c;
    __syncthreads();
    #pragma unroll
    for (int off = 1; off < NTHR; off <<= 1) {
        int v = (tid >= off) ? s_pref[tid - off] : 0;
        __syncthreads();
        s_pref[tid] += v;
        __syncthreads();
    }
    int excl = s_pref[tid] - c;
    int total = s_pref[NTHR - 1];
    if (c > 0 && excl < 64) {
        int k = excl;
        if (i64) {
            const long long* src = (const long long*)edges;
            const long long* dst = src + n_edges;
            for (long long e = base8; e < nv; e += stride8) {
                #pragma unroll
                for (int q = 0; q < 8; q++)
                    if ((int)dst[e + q] == agent) { if (k < 64) s_list[k] = (int)src[e + q]; k++; }
            }
            if (bid == 0 && tid == 0)
                for (long long e = nv; e < n_edges; e++)
                    if ((int)dst[e] == agent) { if (k < 64) s_list[k] = (int)src[e]; k++; }
        } else {
            const int* src = (const int*)edges;
            const int* dst = src + n_edges;
            for (long long e = base8; e < nv; e += stride8) {
                #pragma unroll
                for (int q = 0; q < 8; q++)
                    if (dst[e + q] == agent) { if (k < 64) s_list[k] = src[e + q]; k++; }
            }
            if (bid == 0 && tid == 0)
                for (long long e = nv; e < n_edges; e++)
                    if (dst[e] == agent) { if (k < 64) s_list[k] = src[e]; k++; }
        }
    }
    __syncthreads();
    {
        int* reg = wsi + OFF_PBM + bid * PBM_STRIDE;
        int tw = total < 64 ? total : 64;
        if (tid < tw) AST(&reg[1 + tid], s_list[tid]);
        __syncthreads();                       // all srcs stored
        if (tid == 0) {
            __threadfence();                   // srcs visible before header
            AST(&reg[0], tw + 1);              // header: count+1 (0 / 0xAA invalid)
        }
    }

    // ---- phase 2: poll all 256 headers valid, rebuild list ----
    int bc = 0;
    if (tid < NBLK) {
        const int* hdr = &wsi[OFF_PBM + tid * PBM_STRIDE];
        int h;
        while ((unsigned)((h = ALD(hdr)) - 1) > 64u)
            __builtin_amdgcn_s_sleep(1);
        __hip_atomic_load(hdr, __ATOMIC_ACQUIRE, __HIP_MEMORY_SCOPE_AGENT);
        bc = h - 1;
    }
    s_pref[tid] = bc;
    __syncthreads();
    #pragma unroll
    for (int off = 1; off < NTHR; off <<= 1) {
        int v = (tid >= off) ? s_pref[tid - off] : 0;
        __syncthreads();
        s_pref[tid] += v;
        __syncthreads();
    }
    int excl2 = s_pref[tid] - bc;
    int mc = s_pref[NTHR - 1];
    int m = mc < MAXG ? mc : MAXG;
    if (tid < NBLK) {
        for (int i = 0; i < bc; i++) {
            int g = excl2 + i;
            if (g < MAXG) s_nodes[1 + g] = ALD(&wsi[OFF_PBM + tid * PBM_STRIDE + 1 + i]);
        }
    }
    if (tid == 0) s_nodes[0] = agent;
    for (int i = tid; i < HASHN; i += NTHR) { s_hkey[i] = -1; s_hval[i] = 0x7fffffff; }
    for (int i = tid; i <= m; i += NTHR) s_cnt[i] = 0;
    __syncthreads();

    // parallel deterministic insert: CAS key, atomicMin value (min-j representative)
    for (int j = tid; j <= m; j += NTHR) {
        int key = s_nodes[j];
        unsigned h = hash_n(key);
        while (true) {
            int prev = atomicCAS(&s_hkey[h], -1, key);
            if (prev == -1 || prev == key) { atomicMin(&s_hval[h], j); break; }
            h = (h + 1) & (HASHN - 1);
        }
    }
    __syncthreads();

    // blocks 0..7: L3-prefetch the needed state rows (overlaps degree count)
    if (bid < 8) {
        int esz = b16 ? 2 : 4;
        int chunks = (D_IN * esz) >> 6;
        for (int i = tid; i < (m + 1) * chunks; i += NTHR) {
            int j = i / chunks, ch = i - j * chunks;
            long long row = s_nodes[j];
            unsigned v = *(const unsigned*)((const char*)state + row * D_IN * esz + ch * 64);
            asm volatile("" :: "v"(v));
        }
    }

    // degree count over the SAME slice (L2-hot)
    auto probe = [&](int d) {
        unsigned h = hash_n(d);
        while (true) {
            int k = s_hkey[h];
            if (k == -1) break;
            if (k == d) { atomicAdd(&s_cnt[s_hval[h]], 1); break; }
            h = (h + 1) & (HASHN - 1);
        }
    };
    if (i64) {
        const long long* dst = (const long long*)edges + n_edges;
        for (long long e = base8; e < nv; e += stride8) {
            long2 a0 = *(const long2*)(dst + e);
            long2 a1 = *(const long2*)(dst + e + 2);
            long2 a2 = *(const long2*)(dst + e + 4);
            long2 a3 = *(const long2*)(dst + e + 6);
            probe((int)a0.x); probe((int)a0.y); probe((int)a1.x); probe((int)a1.y);
            probe((int)a2.x); probe((int)a2.y); probe((int)a3.x); probe((int)a3.y);
        }
        if (bid == 0 && tid == 0)
            for (long long e = nv; e < n_edges; e++) probe((int)dst[e]);
    } else {
        const int* dst = (const int*)edges + n_edges;
        for (long long e = base8; e < nv; e += stride8) {
            int4 a = *(const int4*)(dst + e);
            int4 b = *(const int4*)(dst + e + 4);
            probe(a.x); probe(a.y); probe(a.z); probe(a.w);
            probe(b.x); probe(b.y); probe(b.z); probe(b.w);
        }
        if (bid == 0 && tid == 0)
            for (long long e = nv; e < n_edges; e++) probe(dst[e]);
    }
    __syncthreads();
    // overwrite private partial region (all m+1 entries, unconditional)
    {
        int* pbc = wsi + OFF_PBC + bid * PBC_STRIDE;
        for (int j = tid; j <= m; j += NTHR) pbc[j] = s_cnt[j];
    }
    if (bid == 0) {
        if (tid == 0) wsi[OFF_M] = m;
        for (int i = tid; i < m; i += NTHR) wsi[OFF_CM + i] = s_nodes[1 + i];
        for (int j = tid; j <= m; j += NTHR) {
            int key = s_nodes[j];
            unsigned h = hash_n(key);
            while (s_hkey[h] != key) h = (h + 1) & (HASHN - 1);
            wsi[OFF_MAP + j] = s_hval[h];
        }
    }
}

__device__ __forceinline__ float ln256(float v, const void* lnw, const void* lnb,
                                       float* s_red, int tid, bool b16) {
    if (tid < 256) {
        float x = v;
        #pragma unroll
        for (int o = 32; o > 0; o >>= 1) x += __shfl_down(x, o);
        if ((tid & 63) == 0) s_red[tid >> 6] = x;
    }
    __syncthreads();
    float mu = (s_red[0] + s_red[1] + s_red[2] + s_red[3]) * (1.0f / 256.0f);
    if (tid < 256) {
        float dd = v - mu;
        float x = dd * dd;
        #pragma unroll
        for (int o = 32; o > 0; o >>= 1) x += __shfl_down(x, o);
        if ((tid & 63) == 0) s_red[4 + (tid >> 6)] = x;
    }
    __syncthreads();
    float var = (s_red[4] + s_red[5] + s_red[6] + s_red[7]) * (1.0f / 256.0f);
    float y = 0.0f;
    if (tid < 256)
        y = fmaxf((v - mu) * rsqrtf(var + 1e-5f) * ldf(lnw, tid, b16) + ldf(lnb, tid, b16), 0.0f);
    __syncthreads();
    return y;
}

// C: 25-block MLP pipeline, LDS-preloaded weight slices, producer-only barriers.
// Conv blocks first reduce the 256 per-block degree partials in LDS.
__global__ void __launch_bounds__(NT_C) k_C(
    const void* state, const int* agent_p,
    const void* conv_w, const void* conv_b,
    const void* fc1_w, const void* fc1_b, const void* ln1_w, const void* ln1_b,
    const void* fc2_w, const void* fc2_b, const void* ln2_w, const void* ln2_b,
    const void* mu_w, const void* mu_b,
    int* wsi, void* out)
{
    __shared__ float s_wl[8192];     // 32KB weight slice
    __shared__ float s_g[1024];      // gather scratch (8 j-groups x 128 dims)
    __shared__ float s_in[D_HID];
    __shared__ float s_part[NT_C];
    __shared__ float s_xs[D_IN];
    __shared__ float s_red[8];
    __shared__ int   s_src[MAXG];
    __shared__ float s_w[MAXG];
    __shared__ int   s_deg[MAXG + 1];
    __shared__ int   s_b16;

    int tid = threadIdx.x, bid = blockIdx.x;
    bool b16 = detect_b16(state, tid, &s_b16) != 0;
    float* wsf = (float*)wsi;
    int* bar = wsi + OFF_BAR;

    // ---- preload weight slice into LDS (before any waiting) ----
    if (bid < 8) {
        int o0 = bid * 32;
        for (int i = tid; i < D_IN * 32; i += NT_C)
            s_wl[i] = ldf(conv_w, (long long)(i >> 5) * D_HID + o0 + (i & 31), b16);
    } else if (bid < 16) {
        int o0 = (bid - 8) * 32;
        for (int i = tid; i < D_HID * 32; i += NT_C)
            s_wl[i] = ldf(fc1_w, (long long)(i >> 5) * D_HID + o0 + (i & 31), b16);
    } else if (bid < 24) {
        int o0 = (bid - 16) * 32;
        for (int i = tid; i < D_HID * 32; i += NT_C)
            s_wl[i] = ldf(fc2_w, (long long)(i >> 5) * D_HID + o0 + (i & 31), b16);
    } else {
        for (int i = tid; i < D_HID * 8; i += NT_C)
            s_wl[i] = ldf(mu_w, i, b16);
    }

    // ---- conv blocks 0..7: deg reduce + gather + LDS matvec -> H0 ----
    if (bid < 8) {
        int m = wsi[OFF_M];
        m = m < MAXG ? m : MAXG;
        int agent = agent_p[0];
        for (int i = tid; i <= m; i += NT_C) s_deg[i] = 0;
        __syncthreads();
        // reduce 256 partial regions: (m+1) nodes x 8 chunks of 32 regions
        for (int idx = tid; idx < (m + 1) * 8; idx += NT_C) {
            int j = idx >> 3, b0 = (idx & 7) * 32;
            int p = 0;
            #pragma unroll 8
            for (int b = b0; b < b0 + 32; b++)
                p += wsi[OFF_PBC + b * PBC_STRIDE + j];
            atomicAdd(&s_deg[j], p);
        }
        __syncthreads();
        float dinv_a = rsqrtf((float)(s_deg[0] + 1));
        for (int i = tid; i < m; i += NT_C) {
            s_src[i] = wsi[OFF_CM + i];
            int r = wsi[OFF_MAP + 1 + i];
            s_w[i] = dinv_a * rsqrtf((float)(s_deg[r] + 1));
        }
        __syncthreads();
        // 8 j-groups x 64 d-pairs (state rows L3-warm from k_AB prefetch)
        int jg = tid >> 6;
        int d2 = (tid & 63) * 2;
        float a0 = 0.0f, a1 = 0.0f;
        if (jg == 0) {
            float sa, sb;
            ld2(state, (long long)agent * D_IN + d2, b16, sa, sb);
            a0 = dinv_a * dinv_a * sa;
            a1 = dinv_a * dinv_a * sb;
        }
        for (int j = jg; j < m; j += 8) {
            float sa, sb;
            ld2(state, (long long)s_src[j] * D_IN + d2, b16, sa, sb);
            float w = s_w[j];
            a0 += w * sa;
            a1 += w * sb;
        }
        s_g[jg * 128 + d2]     = a0;
        s_g[jg * 128 + d2 + 1] = a1;
        __syncthreads();
        if (tid < D_IN) {
            float acc = 0.0f;
            #pragma unroll
            for (int g = 0; g < 8; g++) acc += s_g[g * 128 + tid];
            s_xs[tid] = acc;
        }
        __syncthreads();
        int c = tid & 31, ks = tid >> 5;   // 16 k-slices of 8
        float a = 0.0f;
        #pragma unroll 8
        for (int k = ks * 8; k < ks * 8 + 8; k++)
            a += s_xs[k] * s_wl[k * 32 + c];
        s_part[tid] = a;
        __syncthreads();
        if (tid < 32) {
            int oo = bid * 32 + tid;
            float h = ldf(conv_b, oo, b16);
            #pragma unroll
            for (int s2 = 0; s2 < 16; s2++) h += s_part[s2 * 32 + tid];
            AST(&wsf[OFF_H0 + oo], fmaxf(h, 0.0f));
        }
        bar_arrive(&bar[0]);
        return;
    }

    // ---- fc1 blocks 8..15: wait conv, LDS matvec -> h1raw ----
    if (bid < 16) {
        bar_wait(&bar[0], 8);
        if (tid < D_HID) s_in[tid] = ALD(&wsf[OFF_H0 + tid]);
        __syncthreads();
        int c = tid & 31, ks = tid >> 5;   // 16 slices x 16 k
        float a = 0.0f;
        #pragma unroll 8
        for (int k = ks * 16; k < ks * 16 + 16; k++)
            a += s_in[k] * s_wl[k * 32 + c];
        s_part[tid] = a;
        __syncthreads();
        if (tid < 32) {
            int oo = (bid - 8) * 32 + tid;
            float h = ldf(fc1_b, oo, b16);
            #pragma unroll
            for (int s2 = 0; s2 < 16; s2++) h += s_part[s2 * 32 + tid];
            AST(&wsf[OFF_H1 + oo], h);
        }
        bar_arrive(&bar[1]);
        return;
    }

    // ---- fc2 blocks 16..23: wait fc1, LN1+relu inline, matvec -> h2raw ----
    if (bid < 24) {
        bar_wait(&bar[1], 8);
        float v = (tid < D_HID) ? ALD(&wsf[OFF_H1 + tid]) : 0.0f;
        float y = ln256(v, ln1_w, ln1_b, s_red, tid, b16);
        if (tid < D_HID) s_in[tid] = y;
        __syncthreads();
        int c = tid & 31, ks = tid >> 5;
        float a = 0.0f;
        #pragma unroll 8
        for (int k = ks * 16; k < ks * 16 + 16; k++)
            a += s_in[k] * s_wl[k * 32 + c];
        s_part[tid] = a;
        __syncthreads();
        if (tid < 32) {
            int oo = (bid - 16) * 32 + tid;
            float h = ldf(fc2_b, oo, b16);
            #pragma unroll
            for (int s2 = 0; s2 < 16; s2++) h += s_part[s2 * 32 + tid];
            AST(&wsf[OFF_H2 + oo], h);
        }
        bar_arrive(&bar[2]);
        return;
    }

    // ---- mu block 24: wait fc2, LN2+relu, 256x8 LDS matvec, sigmoid ----
    {
        bar_wait(&bar[2], 8);
        float v = (tid < D_HID) ? ALD(&wsf[OFF_H2 + tid]) : 0.0f;
        float y = ln256(v, ln2_w, ln2_b, s_red, tid, b16);
        if (tid < D_HID) s_in[tid] = y;
        __syncthreads();
        int o = tid & 7, ks = tid >> 3;   // 64 slices x 4 k
        float a = 0.0f;
        #pragma unroll
        for (int k = ks * 4; k < ks * 4 + 4; k++)
            a += s_in[k] * s_wl[k * 8 + o];
        s_part[tid] = a;
        __syncthreads();
        if (tid < 8) {
            float acc = ldf(mu_b, tid, b16);
            #pragma unroll
            for (int s2 = 0; s2 < 64; s2++) acc += s_part[s2 * 8 + tid];
            float r = 1.0f / (1.0f + expf(-acc));
            if (b16) ((__hip_bfloat16*)out)[tid] = __float2bfloat16(r);
            else     ((float*)out)[tid] = r;
        }
    }
}

extern "C" void kernel_launch(void* const* d_in, const int* in_sizes, int n_in,
                              void* d_out, int out_size, void* d_ws, size_t ws_size,
                              hipStream_t stream) {
    const void* state = d_in[0];
    const void* edges = d_in[1];
    const int* agent = (const int*)d_in[2];
    int* wsi = (int*)d_ws;
    long long n_edges = in_sizes[1] / 2;

    k_AB<<<NBLK, NTHR, 0, stream>>>(edges, state, agent,
                                    d_in[3], d_in[5], d_in[9], d_in[13],
                                    wsi, n_edges);
    k_C<<<25, NT_C, 0, stream>>>(state, agent,
                                 d_in[3], d_in[4],
                                 d_in[5], d_in[6], d_in[7], d_in[8],
                                 d_in[9], d_in[10], d_in[11], d_in[12],
                                 d_in[13], d_in[14],
                                 wsi, d_out);
}

// Round 15
// 31.087 us; speedup vs baseline: 1.3100x; 1.3100x over previous
//
#include <hip/hip_runtime.h>
#include <hip/hip_bf16.h>

#define D_IN  128
#define D_HID 256
#define NB_A  256
#define NT_A  1024
#define NB_B  256
#define NT_B  1024
#define NT_C  512
#define MAXG  512
#define HASHN 2048
#define PBM_STRIDE 72

// ws int layout:
//  [0..7]        barrier slots for kernel C (zeroed by A block 0)
//  [16]          m (compact match count, written by B block 0)
//  [1024..19456] per-A-block match regions (NB_A x PBM_STRIDE)
//  [20480..]     compact match src list (MAXG)
//  [21504..]     map j -> representative index r (MAXG+1 entries, j=0 agent)
//  [24576..]     degree sums, PADDED: counter r lives at OFF_DEG + r*16 (one line each)
//  floats:       [33024]=h0[256], [33536]=h1raw[256], [34048]=h2raw[256]
#define OFF_BAR  0
#define OFF_M    16
#define OFF_PBM  1024
#define OFF_CM   20480
#define OFF_MAP  21504
#define OFF_DEG  24576
#define OFF_H0   33024
#define OFF_H1   33536
#define OFF_H2   34048

#define ALD(p)   __hip_atomic_load((p),      __ATOMIC_RELAXED, __HIP_MEMORY_SCOPE_AGENT)
#define AST(p,v) __hip_atomic_store((p),(v), __ATOMIC_RELAXED, __HIP_MEMORY_SCOPE_AGENT)

__device__ __forceinline__ float ldf(const void* p, long long i, bool b16) {
    if (b16) {
        unsigned short u = ((const unsigned short*)p)[i];
        return __uint_as_float(((unsigned int)u) << 16);
    }
    return ((const float*)p)[i];
}

// paired load of elements i, i+1 (i even)
__device__ __forceinline__ void ld2(const void* p, long long i, bool b16, float& a, float& b) {
    if (b16) {
        unsigned int u = ((const unsigned int*)p)[i >> 1];
        a = __uint_as_float(u << 16);
        b = __uint_as_float(u & 0xffff0000u);
    } else {
        float2 v = ((const float2*)p)[i >> 1];
        a = v.x; b = v.y;
    }
}

__device__ __forceinline__ unsigned hash_n(int key) {
    return (((unsigned)key * 2654435761u) >> 21) & (HASHN - 1);
}

__device__ __forceinline__ int detect_i64(const void* edges, int tid, int* s) {
    if (tid < 64) {
        const unsigned* w = (const unsigned*)edges;
        unsigned long long b = __ballot(w[2 * tid + 1] == 0u);
        if (tid == 0) *s = (b == ~0ULL) ? 1 : 0;
    }
    __syncthreads();
    return *s;
}

__device__ __forceinline__ int detect_b16(const void* state, int tid, int* s) {
    if (tid < 64) {
        const unsigned short* p = (const unsigned short*)state;
        unsigned short v = p[tid];
        int e = (v >> 7) & 0xff;
        unsigned long long b = __ballot(v == 0 || (e >= 90 && e <= 140));
        if (tid == 0) *s = (b == ~0ULL) ? 1 : 0;
    }
    __syncthreads();
    return *s;
}

// producer-side arrival: one fenced RELEASE add, no spin.
__device__ __forceinline__ void bar_arrive(int* slot) {
    __syncthreads();
    if (threadIdx.x == 0) {
        __threadfence();
        __hip_atomic_fetch_add(slot, 1, __ATOMIC_RELEASE, __HIP_MEMORY_SCOPE_AGENT);
    }
}

// consumer-side wait: RELAXED spin (R8 lesson: no acquire polling), fence on exit.
__device__ __forceinline__ void bar_wait(int* slot, int cnt) {
    if (threadIdx.x == 0) {
        while (__hip_atomic_load(slot, __ATOMIC_RELAXED, __HIP_MEMORY_SCOPE_AGENT) < cnt)
            __builtin_amdgcn_s_sleep(2);
        __threadfence();
    }
    __syncthreads();
}

// A: zero control state (block 0) + 8-wide match scan + weight L3-prefetch.
// 1024 threads/block: 16 waves/CU, each thread handles <=1 chunk of 8 edges.
__global__ void __launch_bounds__(NT_A) k_A(const void* edges, const void* state,
                                            const int* agent_p,
                                            const void* w0, const void* w1,
                                            const void* w2, const void* w3,
                                            int* wsi, long long n_edges) {
    __shared__ int s_pref[NT_A];
    __shared__ int s_list[64];
    __shared__ int s_i64, s_b16;
    int tid = threadIdx.x, bid = blockIdx.x;
    int i64 = detect_i64(edges, tid, &s_i64);
    int b16 = detect_b16(state, tid, &s_b16);

    if (bid == 0) {
        if (tid < 8) AST(&wsi[OFF_BAR + tid], 0);
        for (int i = tid; i < (MAXG + 1) * 16; i += NT_A) AST(&wsi[OFF_DEG + i], 0);
    }

    // prefetch weights into L3: one dword per 64B line, spread over the grid
    {
        int esz = b16 ? 2 : 4;
        long long gt = (long long)bid * NT_A + tid;
        const void* arr[4] = { w0, w1, w2, w3 };
        const int elems[4] = { D_IN * D_HID, D_HID * D_HID, D_HID * D_HID, D_HID * 8 };
        long long base = 0;
        #pragma unroll
        for (int a = 0; a < 4; a++) {
            long long lines = ((long long)elems[a] * esz) >> 6;
            long long idx = gt - base;
            if (idx >= 0 && idx < lines) {
                unsigned v = *(const unsigned*)((const char*)arr[a] + (idx << 6));
                asm volatile("" :: "v"(v));
            }
            base += lines;
        }
    }

    int agent = agent_p[0];
    long long base8 = ((long long)bid * NT_A + tid) * 8;
    const long long stride8 = (long long)NB_A * NT_A * 8;
    long long nv = n_edges & ~7LL;
    int c = 0;
    if (i64) {
        const long long* dst = (const long long*)edges + n_edges;
        for (long long e = base8; e < nv; e += stride8) {
            long2 a0 = *(const long2*)(dst + e);
            long2 a1 = *(const long2*)(dst + e + 2);
            long2 a2 = *(const long2*)(dst + e + 4);
            long2 a3 = *(const long2*)(dst + e + 6);
            c += ((int)a0.x == agent) + ((int)a0.y == agent)
               + ((int)a1.x == agent) + ((int)a1.y == agent)
               + ((int)a2.x == agent) + ((int)a2.y == agent)
               + ((int)a3.x == agent) + ((int)a3.y == agent);
        }
        if (bid == 0 && tid == 0)
            for (long long e = nv; e < n_edges; e++) c += ((int)dst[e] == agent);
    } else {
        const int* dst = (const int*)edges + n_edges;
        for (long long e = base8; e < nv; e += stride8) {
            int4 a = *(const int4*)(dst + e);
            int4 b = *(const int4*)(dst + e + 4);
            c += (a.x == agent) + (a.y == agent) + (a.z == agent) + (a.w == agent)
               + (b.x == agent) + (b.y == agent) + (b.z == agent) + (b.w == agent);
        }
        if (bid == 0 && tid == 0)
            for (long long e = nv; e < n_edges; e++) c += (dst[e] == agent);
    }
    s_pref[tid] = c;
    __syncthreads();
    #pragma unroll
    for (int off = 1; off < NT_A; off <<= 1) {
        int v = (tid >= off) ? s_pref[tid - off] : 0;
        __syncthreads();
        s_pref[tid] += v;
        __syncthreads();
    }
    int excl = s_pref[tid] - c;
    int total = s_pref[NT_A - 1];
    if (c > 0 && excl < 64) {
        int k = excl;
        if (i64) {
            const long long* src = (const long long*)edges;
            const long long* dst = src + n_edges;
            for (long long e = base8; e < nv; e += stride8) {
                #pragma unroll
                for (int q = 0; q < 8; q++) {
                    if ((int)dst[e + q] == agent) { if (k < 64) s_list[k] = (int)src[e + q]; k++; }
                }
            }
            if (bid == 0 && tid == 0)
                for (long long e = nv; e < n_edges; e++)
                    if ((int)dst[e] == agent) { if (k < 64) s_list[k] = (int)src[e]; k++; }
        } else {
            const int* src = (const int*)edges;
            const int* dst = src + n_edges;
            for (long long e = base8; e < nv; e += stride8) {
                #pragma unroll
                for (int q = 0; q < 8; q++) {
                    if (dst[e + q] == agent) { if (k < 64) s_list[k] = src[e + q]; k++; }
                }
            }
            if (bid == 0 && tid == 0)
                for (long long e = nv; e < n_edges; e++)
                    if (dst[e] == agent) { if (k < 64) s_list[k] = src[e]; k++; }
        }
    }
    __syncthreads();
    int* reg = wsi + OFF_PBM + bid * PBM_STRIDE;
    int tw = total < 64 ? total : 64;
    if (tid == 0) reg[0] = tw;
    if (tid < tw) reg[1 + tid] = s_list[tid];
}

// B: rebuild compact match list, PARALLEL deterministic hash (CAS key + min-j
// value), 8-wide degree count into line-padded DEG, export list + j->r map.
// Blocks 0..7 also L3-prefetch the needed state rows. 1024 threads/block.
__global__ void __launch_bounds__(NT_B) k_B(const void* edges, const void* state,
                                            const int* agent_p,
                                            int* wsi, long long n_edges) {
    __shared__ int s_pref[NT_B];
    __shared__ int s_nodes[MAXG + 1];
    __shared__ int s_hkey[HASHN];
    __shared__ int s_hval[HASHN];
    __shared__ int s_cnt[MAXG + 1];
    __shared__ int s_i64, s_b16;
    int tid = threadIdx.x, bid = blockIdx.x;
    int i64 = detect_i64(edges, tid, &s_i64);
    bool b16 = detect_b16(state, tid, &s_b16) != 0;

    int bc = 0;
    if (tid < NB_A) {
        bc = wsi[OFF_PBM + tid * PBM_STRIDE];
        bc = bc < 64 ? (bc < 0 ? 0 : bc) : 64;
    }
    s_pref[tid] = bc;
    __syncthreads();
    #pragma unroll
    for (int off = 1; off < NT_B; off <<= 1) {
        int v = (tid >= off) ? s_pref[tid - off] : 0;
        __syncthreads();
        s_pref[tid] += v;
        __syncthreads();
    }
    int excl = s_pref[tid] - bc;
    int mc = s_pref[NT_B - 1];
    int m = mc < MAXG ? mc : MAXG;
    if (tid < NB_A) {
        for (int i = 0; i < bc; i++) {
            int g = excl + i;
            if (g < MAXG) s_nodes[1 + g] = wsi[OFF_PBM + tid * PBM_STRIDE + 1 + i];
        }
    }
    if (tid == 0) s_nodes[0] = agent_p[0];
    for (int i = tid; i < HASHN; i += NT_B) { s_hkey[i] = -1; s_hval[i] = 0x7fffffff; }
    for (int i = tid; i <= m; i += NT_B) s_cnt[i] = 0;
    __syncthreads();

    // parallel deterministic insert: CAS the key, atomicMin the value (first j).
    for (int j = tid; j <= m; j += NT_B) {
        int key = s_nodes[j];
        unsigned h = hash_n(key);
        while (true) {
            int prev = atomicCAS(&s_hkey[h], -1, key);
            if (prev == -1 || prev == key) { atomicMin(&s_hval[h], j); break; }
            h = (h + 1) & (HASHN - 1);
        }
    }
    __syncthreads();

    // blocks 0..7: L3-prefetch the m+1 needed state rows (overlaps degree count)
    if (bid < 8) {
        int esz = b16 ? 2 : 4;
        int chunks = (D_IN * esz) >> 6;   // 64B lines per row
        for (int i = tid; i < (m + 1) * chunks; i += NT_B) {
            int j = i / chunks, ch = i - j * chunks;
            long long row = s_nodes[j];
            unsigned v = *(const unsigned*)((const char*)state + row * D_IN * esz + ch * 64);
            asm volatile("" :: "v"(v));
        }
    }

    auto probe = [&](int d) {
        unsigned h = hash_n(d);
        while (true) {
            int k = s_hkey[h];
            if (k == -1) break;
            if (k == d) { atomicAdd(&s_cnt[s_hval[h]], 1); break; }
            h = (h + 1) & (HASHN - 1);
        }
    };

    long long base8 = ((long long)bid * NT_B + tid) * 8;
    const long long stride8 = (long long)NB_B * NT_B * 8;
    long long nv = n_edges & ~7LL;
    if (i64) {
        const long long* dst = (const long long*)edges + n_edges;
        for (long long e = base8; e < nv; e += stride8) {
            long2 a0 = *(const long2*)(dst + e);
            long2 a1 = *(const long2*)(dst + e + 2);
            long2 a2 = *(const long2*)(dst + e + 4);
            long2 a3 = *(const long2*)(dst + e + 6);
            probe((int)a0.x); probe((int)a0.y); probe((int)a1.x); probe((int)a1.y);
            probe((int)a2.x); probe((int)a2.y); probe((int)a3.x); probe((int)a3.y);
        }
        if (bid == 0 && tid == 0)
            for (long long e = nv; e < n_edges; e++) probe((int)dst[e]);
    } else {
        const int* dst = (const int*)edges + n_edges;
        for (long long e = base8; e < nv; e += stride8) {
            int4 a = *(const int4*)(dst + e);
            int4 b = *(const int4*)(dst + e + 4);
            probe(a.x); probe(a.y); probe(a.z); probe(a.w);
            probe(b.x); probe(b.y); probe(b.z); probe(b.w);
        }
        if (bid == 0 && tid == 0)
            for (long long e = nv; e < n_edges; e++) probe(dst[e]);
    }
    __syncthreads();
    // export: one padded cache line per representative counter
    for (int j = tid; j <= m; j += NT_B)
        if (s_cnt[j]) atomicAdd(&wsi[OFF_DEG + j * 16], s_cnt[j]);
    if (bid == 0) {
        if (tid == 0) wsi[OFF_M] = m;
        for (int i = tid; i < m; i += NT_B) wsi[OFF_CM + i] = s_nodes[1 + i];
        for (int j = tid; j <= m; j += NT_B) {
            int key = s_nodes[j];
            unsigned h = hash_n(key);
            while (s_hkey[h] != key) h = (h + 1) & (HASHN - 1);
            wsi[OFF_MAP + j] = s_hval[h];
        }
    }
}

__device__ __forceinline__ float ln256(float v, const void* lnw, const void* lnb,
                                       float* s_red, int tid, bool b16) {
    if (tid < 256) {
        float x = v;
        #pragma unroll
        for (int o = 32; o > 0; o >>= 1) x += __shfl_down(x, o);
        if ((tid & 63) == 0) s_red[tid >> 6] = x;
    }
    __syncthreads();
    float mu = (s_red[0] + s_red[1] + s_red[2] + s_red[3]) * (1.0f / 256.0f);
    if (tid < 256) {
        float dd = v - mu;
        float x = dd * dd;
        #pragma unroll
        for (int o = 32; o > 0; o >>= 1) x += __shfl_down(x, o);
        if ((tid & 63) == 0) s_red[4 + (tid >> 6)] = x;
    }
    __syncthreads();
    float var = (s_red[4] + s_red[5] + s_red[6] + s_red[7]) * (1.0f / 256.0f);
    float y = 0.0f;
    if (tid < 256)
        y = fmaxf((v - mu) * rsqrtf(var + 1e-5f) * ldf(lnw, tid, b16) + ldf(lnb, tid, b16), 0.0f);
    __syncthreads();
    return y;
}

// C: 25-block MLP pipeline, LDS-preloaded weight slices, producer-only barriers.
__global__ void __launch_bounds__(NT_C) k_C(
    const void* state, const int* agent_p,
    const void* conv_w, const void* conv_b,
    const void* fc1_w, const void* fc1_b, const void* ln1_w, const void* ln1_b,
    const void* fc2_w, const void* fc2_b, const void* ln2_w, const void* ln2_b,
    const void* mu_w, const void* mu_b,
    int* wsi, void* out)
{
    __shared__ float s_wl[8192];     // 32KB weight slice
    __shared__ float s_g[1024];      // gather scratch (8 j-groups x 128 dims)
    __shared__ float s_in[D_HID];
    __shared__ float s_part[NT_C];
    __shared__ float s_xs[D_IN];
    __shared__ float s_red[8];
    __shared__ int   s_src[MAXG];
    __shared__ float s_w[MAXG];
    __shared__ int   s_b16;

    int tid = threadIdx.x, bid = blockIdx.x;
    bool b16 = detect_b16(state, tid, &s_b16) != 0;
    float* wsf = (float*)wsi;
    int* bar = wsi + OFF_BAR;

    // ---- preload weight slice into LDS (before any waiting) ----
    if (bid < 8) {
        int o0 = bid * 32;
        for (int i = tid; i < D_IN * 32; i += NT_C)
            s_wl[i] = ldf(conv_w, (long long)(i >> 5) * D_HID + o0 + (i & 31), b16);
    } else if (bid < 16) {
        int o0 = (bid - 8) * 32;
        for (int i = tid; i < D_HID * 32; i += NT_C)
            s_wl[i] = ldf(fc1_w, (long long)(i >> 5) * D_HID + o0 + (i & 31), b16);
    } else if (bid < 24) {
        int o0 = (bid - 16) * 32;
        for (int i = tid; i < D_HID * 32; i += NT_C)
            s_wl[i] = ldf(fc2_w, (long long)(i >> 5) * D_HID + o0 + (i & 31), b16);
    } else {
        for (int i = tid; i < D_HID * 8; i += NT_C)
            s_wl[i] = ldf(mu_w, i, b16);
    }

    // ---- conv blocks 0..7: gather (8-way split) + LDS matvec -> H0 ----
    if (bid < 8) {
        int m = wsi[OFF_M];
        m = m < MAXG ? m : MAXG;
        int agent = agent_p[0];
        float dinv_a = rsqrtf((float)(ALD(&wsi[OFF_DEG]) + 1));
        for (int i = tid; i < m; i += NT_C) {
            s_src[i] = wsi[OFF_CM + i];
            int u = wsi[OFF_MAP + 1 + i];
            s_w[i] = dinv_a * rsqrtf((float)(ALD(&wsi[OFF_DEG + u * 16]) + 1));
        }
        __syncthreads();
        // 8 j-groups x 64 d-pairs (state rows L3-warm from k_B prefetch)
        int jg = tid >> 6;
        int d2 = (tid & 63) * 2;
        float a0 = 0.0f, a1 = 0.0f;
        if (jg == 0) {
            float sa, sb;
            ld2(state, (long long)agent * D_IN + d2, b16, sa, sb);
            a0 = dinv_a * dinv_a * sa;
            a1 = dinv_a * dinv_a * sb;
        }
        for (int j = jg; j < m; j += 8) {
            float sa, sb;
            ld2(state, (long long)s_src[j] * D_IN + d2, b16, sa, sb);
            float w = s_w[j];
            a0 += w * sa;
            a1 += w * sb;
        }
        s_g[jg * 128 + d2]     = a0;
        s_g[jg * 128 + d2 + 1] = a1;
        __syncthreads();
        if (tid < D_IN) {
            float acc = 0.0f;
            #pragma unroll
            for (int g = 0; g < 8; g++) acc += s_g[g * 128 + tid];
            s_xs[tid] = acc;
        }
        __syncthreads();
        int c = tid & 31, ks = tid >> 5;   // 16 k-slices of 8
        float a = 0.0f;
        #pragma unroll 8
        for (int k = ks * 8; k < ks * 8 + 8; k++)
            a += s_xs[k] * s_wl[k * 32 + c];
        s_part[tid] = a;
        __syncthreads();
        if (tid < 32) {
            int oo = bid * 32 + tid;
            float h = ldf(conv_b, oo, b16);
            #pragma unroll
            for (int s2 = 0; s2 < 16; s2++) h += s_part[s2 * 32 + tid];
            AST(&wsf[OFF_H0 + oo], fmaxf(h, 0.0f));
        }
        bar_arrive(&bar[0]);
        return;
    }

    // ---- fc1 blocks 8..15: wait conv, LDS matvec -> h1raw ----
    if (bid < 16) {
        bar_wait(&bar[0], 8);
        if (tid < D_HID) s_in[tid] = ALD(&wsf[OFF_H0 + tid]);
        __syncthreads();
        int c = tid & 31, ks = tid >> 5;   // 16 slices x 16 k
        float a = 0.0f;
        #pragma unroll 8
        for (int k = ks * 16; k < ks * 16 + 16; k++)
            a += s_in[k] * s_wl[k * 32 + c];
        s_part[tid] = a;
        __syncthreads();
        if (tid < 32) {
            int oo = (bid - 8) * 32 + tid;
            float h = ldf(fc1_b, oo, b16);
            #pragma unroll
            for (int s2 = 0; s2 < 16; s2++) h += s_part[s2 * 32 + tid];
            AST(&wsf[OFF_H1 + oo], h);
        }
        bar_arrive(&bar[1]);
        return;
    }

    // ---- fc2 blocks 16..23: wait fc1, LN1+relu inline, matvec -> h2raw ----
    if (bid < 24) {
        bar_wait(&bar[1], 8);
        float v = (tid < D_HID) ? ALD(&wsf[OFF_H1 + tid]) : 0.0f;
        float y = ln256(v, ln1_w, ln1_b, s_red, tid, b16);
        if (tid < D_HID) s_in[tid] = y;
        __syncthreads();
        int c = tid & 31, ks = tid >> 5;
        float a = 0.0f;
        #pragma unroll 8
        for (int k = ks * 16; k < ks * 16 + 16; k++)
            a += s_in[k] * s_wl[k * 32 + c];
        s_part[tid] = a;
        __syncthreads();
        if (tid < 32) {
            int oo = (bid - 16) * 32 + tid;
            float h = ldf(fc2_b, oo, b16);
            #pragma unroll
            for (int s2 = 0; s2 < 16; s2++) h += s_part[s2 * 32 + tid];
            AST(&wsf[OFF_H2 + oo], h);
        }
        bar_arrive(&bar[2]);
        return;
    }

    // ---- mu block 24: wait fc2, LN2+relu, 256x8 LDS matvec, sigmoid ----
    {
        bar_wait(&bar[2], 8);
        float v = (tid < D_HID) ? ALD(&wsf[OFF_H2 + tid]) : 0.0f;
        float y = ln256(v, ln2_w, ln2_b, s_red, tid, b16);
        if (tid < D_HID) s_in[tid] = y;
        __syncthreads();
        int o = tid & 7, ks = tid >> 3;   // 64 slices x 4 k
        float a = 0.0f;
        #pragma unroll
        for (int k = ks * 4; k < ks * 4 + 4; k++)
            a += s_in[k] * s_wl[k * 8 + o];
        s_part[tid] = a;
        __syncthreads();
        if (tid < 8) {
            float acc = ldf(mu_b, tid, b16);
            #pragma unroll
            for (int s2 = 0; s2 < 64; s2++) acc += s_part[s2 * 8 + tid];
            float r = 1.0f / (1.0f + expf(-acc));
            if (b16) ((__hip_bfloat16*)out)[tid] = __float2bfloat16(r);
            else     ((float*)out)[tid] = r;
        }
    }
}

extern "C" void kernel_launch(void* const* d_in, const int* in_sizes, int n_in,
                              void* d_out, int out_size, void* d_ws, size_t ws_size,
                              hipStream_t stream) {
    const void* state = d_in[0];
    const void* edges = d_in[1];
    const int* agent = (const int*)d_in[2];
    int* wsi = (int*)d_ws;
    long long n_edges = in_sizes[1] / 2;

    k_A<<<NB_A, NT_A, 0, stream>>>(edges, state, agent,
                                   d_in[3], d_in[5], d_in[9], d_in[13],
                                   wsi, n_edges);
    k_B<<<NB_B, NT_B, 0, stream>>>(edges, state, agent, wsi, n_edges);
    k_C<<<25, NT_C, 0, stream>>>(state, agent,
                                 d_in[3], d_in[4],
                                 d_in[5], d_in[6], d_in[7], d_in[8],
                                 d_in[9], d_in[10], d_in[11], d_in[12],
                                 d_in[13], d_in[14],
                                 wsi, d_out);
}